// Round 8
// baseline (202.177 us; speedup 1.0000x reference)
//
#include <hip/hip_runtime.h>
#include <hip/hip_bf16.h>

typedef unsigned short u16;
typedef unsigned int u32;
typedef __attribute__((ext_vector_type(8))) short short8;   // 8 bf16 for MFMA frags
typedef __attribute__((ext_vector_type(8))) u16 ushort8;
typedef __attribute__((ext_vector_type(4))) float f32x4;

// ---------- constants ----------
#define BB 2048
#define SS 8
#define DNUM 8
#define LL 50
#define EDIM 16
#define FDIM 512
#define HID1 256
#define HID2 128
#define KDNN 1216          // 1160 padded to 64-multiple
#define ROWS (BB*LL)       // 102400

// ---------- helpers ----------
__device__ inline u16 f2bf(float x) {            // HW RNE cvt (compiler packs)
    return __builtin_bit_cast(u16, __float2bfloat16(x));
}
__device__ inline float bf2f(u16 b) {
    u32 u = ((u32)b) << 16;
    return __builtin_bit_cast(float, u);
}
__device__ inline void load16_lds(const void* g, void* l) {
    __builtin_amdgcn_global_load_lds(
        (const __attribute__((address_space(1))) u32*)g,
        (__attribute__((address_space(3))) u32*)l, 16, 0, 0);
}
__device__ inline float wave_sum(float v) {
    #pragma unroll
    for (int off = 32; off > 0; off >>= 1) v += __shfl_xor(v, off, 64);
    return v;
}
__device__ inline float wave_max(float v) {
    #pragma unroll
    for (int off = 32; off > 0; off >>= 1) v = fmaxf(v, __shfl_xor(v, off, 64));
    return v;
}
__device__ inline void cvt8(const float4& a, const float4& b, ushort8& o) {
    o[0]=f2bf(a.x); o[1]=f2bf(a.y); o[2]=f2bf(a.z); o[3]=f2bf(a.w);
    o[4]=f2bf(b.x); o[5]=f2bf(b.y); o[6]=f2bf(b.z); o[7]=f2bf(b.w);
}

// ---------- K0: weight prep (combine + transpose + bf16) ----------
// WHP_S [128n][1024k] PRE-SWIZZLED: within each 64-k tile, elements XOR'd by
//   ((n&7)<<3) so a swizzled ds_read after linear global_load_lds staging is
//   conflict-free (verified R6: conflicts 9.9M -> 33K).
//   k<512 -> Wh = W1b-W1c ; k>=512 -> Wp = W1d
__global__ __launch_bounds__(256) void prep_weights(
    const float* __restrict__ w1, const float* __restrict__ dw1,
    const float* __restrict__ dw2,
    u16* __restrict__ WHP_S, u16* __restrict__ WQ_T,
    u16* __restrict__ W1D_T, u16* __restrict__ W2D_T)
{
    int idx = blockIdx.x * 256 + threadIdx.x;
    if (idx < 131072) {
        int n = idx >> 10, k = idx & 1023;
        float v;
        if (k < 512) v = w1[(512 + k) * 128 + n] - w1[(1024 + k) * 128 + n];
        else         v = w1[(1024 + k) * 128 + n];   // 1536 + (k-512)
        int ks = (k & ~63) | ((k & 63) ^ ((n & 7) << 3));
        WHP_S[n * 1024 + ks] = f2bf(v);
    } else if (idx < 196608) {
        int i = idx - 131072;
        int n = i >> 9, k = i & 511;
        WQ_T[n * 512 + k] = f2bf(w1[k * 128 + n] + w1[(1024 + k) * 128 + n]);
    } else if (idx < 507904) {
        int i = idx - 196608;
        int n = i / KDNN, k = i - n * KDNN;
        W1D_T[i] = (k < 1160) ? f2bf(dw1[k * HID1 + n]) : (u16)0;
    } else if (idx < 540672) {
        int i = idx - 507904;
        int n = i >> 8, k = i & 255;
        W2D_T[i] = f2bf(dw2[k * HID2 + n]);
    }
}

// ---------- K1: per-b gather: sparse emb + dense + feed -> dnn_in (bf16), A_q ----------
__global__ __launch_bounds__(256) void gather_b(
    const int* __restrict__ sparse_ids, const float* __restrict__ dense,
    const int* __restrict__ feedid, const float* __restrict__ emb_tables,
    const float* __restrict__ feed_table,
    u16* __restrict__ dnn_in, u16* __restrict__ A_q)
{
    int b = blockIdx.x, t = threadIdx.x;
    u16* drow = dnn_in + (size_t)b * KDNN;
    if (t < 128) {
        int s = t >> 4, e = t & 15;
        int id = sparse_ids[b * SS + s];
        float v = emb_tables[(size_t)s * 1600000 + (size_t)id * EDIM + e];
        drow[t] = f2bf(v);
    } else if (t < 136) {
        drow[t] = f2bf(dense[b * DNUM + (t - 128)]);
    } else if (t < 192) {
        drow[1160 + (t - 136)] = 0;   // K padding
    }
    int fid = feedid[b];
    float2 f = *(const float2*)&feed_table[(size_t)fid * FDIM + t * 2];
    u16 u0 = f2bf(f.x), u1 = f2bf(f.y);
    drow[136 + t * 2] = u0;
    drow[136 + t * 2 + 1] = u1;
    A_q[(size_t)b * FDIM + t * 2] = u0;
    A_q[(size_t)b * FDIM + t * 2 + 1] = u1;
}

// ---------- K2: generic bf16 MFMA GEMM, templated M-tile ----------
template<int BM, bool RELU, bool OUT_BF16>
__global__ __launch_bounds__(256, 4) void gemm_bt(
    const u16* __restrict__ A, int lda,
    const u16* __restrict__ BT, int ldb,
    const float* __restrict__ bias,
    void* __restrict__ Cv, int M, int N, int K)
{
    constexpr int MI = BM / 32;           // frags per wave in M
    __shared__ u16 As[BM * 64];
    __shared__ u16 Bs[128 * 64];
    int m0 = blockIdx.x * BM, n0 = blockIdx.y * 128;
    int tid = threadIdx.x, wave = tid >> 6, lane = tid & 63;
    int lrow = lane >> 3, lk = (lane & 7) * 8;
    f32x4 acc[MI][4];
    f32x4 zz = {0.f, 0.f, 0.f, 0.f};
    #pragma unroll
    for (int i = 0; i < MI; i++)
        #pragma unroll
        for (int j = 0; j < 4; j++) acc[i][j] = zz;
    int wm = (wave >> 1) * (BM / 2), wn = (wave & 1) * 64;

    for (int kt = 0; kt < K; kt += 64) {
        #pragma unroll
        for (int j = 0; j < MI; ++j) {
            int c = wave * MI + j;
            int row = c * 8 + lrow;
            load16_lds(A + (size_t)(m0 + row) * lda + kt + lk, &As[c * 512]);
        }
        #pragma unroll
        for (int j = 0; j < 4; ++j) {
            int c = wave * 4 + j;
            int row = c * 8 + lrow;
            load16_lds(BT + (size_t)(n0 + row) * ldb + kt + lk, &Bs[c * 512]);
        }
        __syncthreads();
        #pragma unroll
        for (int ks = 0; ks < 2; ++ks) {
            int kk = ks * 32 + (lane >> 4) * 8;
            short8 af[MI], bf[4];
            #pragma unroll
            for (int i = 0; i < MI; i++)
                af[i] = *(const short8*)&As[(wm + i * 16 + (lane & 15)) * 64 + kk];
            #pragma unroll
            for (int j = 0; j < 4; j++)
                bf[j] = *(const short8*)&Bs[(wn + j * 16 + (lane & 15)) * 64 + kk];
            #pragma unroll
            for (int i = 0; i < MI; i++)
                #pragma unroll
                for (int j = 0; j < 4; j++)
                    acc[i][j] = __builtin_amdgcn_mfma_f32_16x16x32_bf16(
                        af[i], bf[j], acc[i][j], 0, 0, 0);
        }
        __syncthreads();
    }
    #pragma unroll
    for (int i = 0; i < MI; i++) {
        #pragma unroll
        for (int j = 0; j < 4; j++) {
            #pragma unroll
            for (int r = 0; r < 4; r++) {
                int row = m0 + wm + i * 16 + (lane >> 4) * 4 + r;
                int col = n0 + wn + j * 16 + (lane & 15);
                float v = acc[i][j][r];
                if (bias) v += bias[col];
                if (RELU) v = fmaxf(v, 0.f);
                size_t off = (size_t)row * N + col;
                if (OUT_BF16) ((u16*)Cv)[off] = f2bf(v);
                else ((float*)Cv)[off] = v;
            }
        }
    }
}

// ---------- K3: DIN GEMM v8 — barrier-free k-loop + manual 2-deep pipeline ----------
// Same macro-structure as R7 (B half fully LDS-resident, one prologue
// barrier), but: NO setprio in the k-loop (it was acting as a scheduling
// fence — R7's compiler emitted a serial 88-VGPR schedule), and the h/q
// gathers are manually software-pipelined in named rotating buffers:
// h 2 kf ahead (~700 cyc cover, L3-latency class), q 1 kf ahead (L2-hot).
// All buffer indices are compile-time constants under full unroll.
__global__ __launch_bounds__(512, 1) void din_gemm(
    const int* __restrict__ hist_ids, const int* __restrict__ feedid,
    const float* __restrict__ feed_table,
    const u16* __restrict__ WHP_S,
    const float* __restrict__ qw, const float* __restrict__ b1,
    const float* __restrict__ w2v, float* __restrict__ scores_part)
{
    __shared__ u16 Bs[64 * 1024];     // 128 KB
    __shared__ int hids[512];
    __shared__ float qbs[12 * 64];
    __shared__ float w2s[64];

    int t = threadIdx.x, wave = t >> 6, lane = t & 63;
    int half = blockIdx.x & 1;
    int m0 = (blockIdx.x >> 1) * 512;
    int b0 = m0 / LL;
    int fr = lane & 15, kgrp = (lane >> 4) * 8;

    // ---- prologue staging ----
    {
        const u16* src = WHP_S + (size_t)half * 64 * 1024;
        #pragma unroll
        for (int c2 = 0; c2 < 16; ++c2)
            load16_lds(src + c2 * 4096 + t * 8, &Bs[c2 * 4096 + t * 8]);
    }
    hids[t] = hist_ids[m0 + t];
    if (t < 64) w2s[t] = w2v[half * 64 + t];
    for (int idx = t; idx < 768; idx += 512) {
        int bi = idx >> 6, cl = idx & 63;
        int bb = b0 + bi; if (bb > BB - 1) bb = BB - 1;
        qbs[idx] = qw[bb * 128 + half * 64 + cl] + b1[half * 64 + cl];
    }
    __syncthreads();   // drains global_load_lds (compiler emits vmcnt(0))

    // ---- per-frag A row pointers ----
    const float* hp[4];
    const float* qp[4];
    #pragma unroll
    for (int i = 0; i < 4; ++i) {
        int rl = wave * 64 + i * 16 + fr;
        int bb = (m0 + rl) / LL;
        hp[i] = feed_table + (size_t)hids[rl] * FDIM + kgrp;
        qp[i] = feed_table + (size_t)feedid[bb] * FDIM + kgrp;
    }

    f32x4 acc[4][4];
    f32x4 zz = {0.f, 0.f, 0.f, 0.f};
    #pragma unroll
    for (int i = 0; i < 4; i++)
        #pragma unroll
        for (int j = 0; j < 4; j++) acc[i][j] = zz;

    // ---- manual pipeline preload: h for kf=0,1 ; q for kf=0 ----
    float4 hbuf[2][4][2];
    float4 qbuf[4][2];
    #pragma unroll
    for (int pp = 0; pp < 2; ++pp)
        #pragma unroll
        for (int i = 0; i < 4; ++i) {
            hbuf[pp][i][0] = *(const float4*)(hp[i] + pp * 32);
            hbuf[pp][i][1] = *(const float4*)(hp[i] + pp * 32 + 4);
        }
    #pragma unroll
    for (int i = 0; i < 4; ++i) {
        qbuf[i][0] = *(const float4*)(qp[i]);
        qbuf[i][1] = *(const float4*)(qp[i] + 4);
    }

    // ---- barrier-free, fence-free k-loop ----
    #pragma unroll
    for (int kf = 0; kf < 16; ++kf) {
        const int kbase = kf * 32;
        const int cur = kf & 1;
        // B fragments (swizzled conflict-free ds_read)
        short8 bh[4], bp[4];
        #pragma unroll
        for (int j = 0; j < 4; ++j) {
            int n = j * 16 + fr;
            int kh = kbase + kgrp;
            int kp = 512 + kbase + kgrp;
            int kkh = (kh & ~63) | ((kh & 63) ^ ((n & 7) << 3));
            int kkp = (kp & ~63) | ((kp & 63) ^ ((n & 7) << 3));
            bh[j] = *(const short8*)&Bs[n * 1024 + kkh];
            bp[j] = *(const short8*)&Bs[n * 1024 + kkp];
        }
        // cvt h and build p = h*q from the pipelined registers
        short8 ah[4], ap[4];
        #pragma unroll
        for (int i = 0; i < 4; ++i) {
            float4 h0 = hbuf[cur][i][0], h1 = hbuf[cur][i][1];
            float4 q0 = qbuf[i][0],      q1 = qbuf[i][1];
            ushort8 hv, pv;
            cvt8(h0, h1, hv);
            float4 p0 = make_float4(h0.x*q0.x, h0.y*q0.y, h0.z*q0.z, h0.w*q0.w);
            float4 p1 = make_float4(h1.x*q1.x, h1.y*q1.y, h1.z*q1.z, h1.w*q1.w);
            cvt8(p0, p1, pv);
            ah[i] = __builtin_bit_cast(short8, hv);
            ap[i] = __builtin_bit_cast(short8, pv);
        }
        // issue next prefetches (h: kf+2 into the slot just consumed; q: kf+1)
        if (kf + 2 < 16) {
            #pragma unroll
            for (int i = 0; i < 4; ++i) {
                hbuf[cur][i][0] = *(const float4*)(hp[i] + kbase + 64);
                hbuf[cur][i][1] = *(const float4*)(hp[i] + kbase + 64 + 4);
            }
        }
        if (kf + 1 < 16) {
            #pragma unroll
            for (int i = 0; i < 4; ++i) {
                qbuf[i][0] = *(const float4*)(qp[i] + kbase + 32);
                qbuf[i][1] = *(const float4*)(qp[i] + kbase + 32 + 4);
            }
        }
        // dual-stream MFMA (no setprio — let the scheduler interleave)
        #pragma unroll
        for (int i = 0; i < 4; ++i)
            #pragma unroll
            for (int j = 0; j < 4; ++j)
                acc[i][j] = __builtin_amdgcn_mfma_f32_16x16x32_bf16(
                    ah[i], bh[j], acc[i][j], 0, 0, 0);
        #pragma unroll
        for (int i = 0; i < 4; ++i)
            #pragma unroll
            for (int j = 0; j < 4; ++j)
                acc[i][j] = __builtin_amdgcn_mfma_f32_16x16x32_bf16(
                    ap[i], bp[j], acc[i][j], 0, 0, 0);
    }

    // ---- epilogue: partial scores for this col-half ----
    float* sp = scores_part + (size_t)half * ROWS + m0;
    #pragma unroll
    for (int i = 0; i < 4; ++i) {
        #pragma unroll
        for (int r = 0; r < 4; ++r) {
            int rl = wave * 64 + i * 16 + (lane >> 4) * 4 + r;
            int bi = (m0 + rl) / LL - b0;
            float s = 0.f;
            #pragma unroll
            for (int j = 0; j < 4; ++j) {
                int cl = j * 16 + fr;
                float v = acc[i][j][r] + qbs[bi * 64 + cl];
                s += fmaxf(v, 0.f) * w2s[cl];
            }
            s += __shfl_xor(s, 1, 64);
            s += __shfl_xor(s, 2, 64);
            s += __shfl_xor(s, 4, 64);
            s += __shfl_xor(s, 8, 64);
            if (fr == 0) sp[rl] = s;
        }
    }
}

// ---------- K4: softmax over L + user_interest (re-gather h, L3-hot) ----------
__global__ __launch_bounds__(256) void softmax_ui(
    const float* __restrict__ scores_part, const int* __restrict__ hist_ids,
    const float* __restrict__ feed_table, u16* __restrict__ dnn_in)
{
    int b = blockIdx.x, t = threadIdx.x;
    int wave = t >> 6, lane = t & 63;
    __shared__ float sc[56];
    __shared__ int hid[56];
    if (t >= 64 && t < 64 + LL) hid[t - 64] = hist_ids[b * LL + (t - 64)];
    if (wave == 0) {
        float x = -1e30f;
        if (lane < LL)
            x = scores_part[b * LL + lane] + scores_part[ROWS + b * LL + lane];
        float mx = wave_max(x);
        float e = (lane < LL) ? __expf(x - mx) : 0.f;
        float s = wave_sum(e);
        if (lane < LL) sc[lane] = e / s;
    }
    __syncthreads();
    int d = t * 2;
    float a0 = 0.f, a1 = 0.f;
    #pragma unroll 5
    for (int l = 0; l < LL; ++l) {
        float2 hv = *(const float2*)&feed_table[(size_t)hid[l] * FDIM + d];
        float al = sc[l];
        a0 += al * hv.x;
        a1 += al * hv.y;
    }
    dnn_in[(size_t)b * KDNN + 648 + d] = f2bf(a0);
    dnn_in[(size_t)b * KDNN + 648 + d + 1] = f2bf(a1);
}

// ---------- K5: MMOE + task heads ----------
__global__ __launch_bounds__(256) void mmoe_head(
    const float* __restrict__ dnn_out, const float* __restrict__ expert_w,
    const float* __restrict__ gate_w, const float* __restrict__ out_w,
    const float* __restrict__ out_b, float* __restrict__ out)
{
    int wave = threadIdx.x >> 6, lane = threadIdx.x & 63;
    int b = blockIdx.x * 4 + wave;
    __shared__ float ds[4][128];
    __shared__ float eo[4][64];
    __shared__ float gt[4][32];
    ds[wave][lane] = dnn_out[b * 128 + lane];
    ds[wave][lane + 64] = dnn_out[b * 128 + 64 + lane];
    __syncthreads();
    int e = lane >> 3, o = lane & 7;
    float acc = 0.f;
    for (int k = 0; k < 128; ++k)
        acc += ds[wave][k] * expert_w[(e * 128 + k) * 8 + o];
    eo[wave][lane] = acc;
    if (lane < 32) {
        int tt = lane >> 3, ee = lane & 7;
        float g = 0.f;
        for (int k = 0; k < 128; ++k)
            g += ds[wave][k] * gate_w[(tt * 128 + k) * 8 + ee];
        float m = g;
        #pragma unroll
        for (int off = 4; off; off >>= 1) m = fmaxf(m, __shfl_xor(m, off, 8));
        float ex = __expf(g - m);
        float s = ex;
        #pragma unroll
        for (int off = 4; off; off >>= 1) s += __shfl_xor(s, off, 8);
        gt[wave][lane] = ex / s;
    }
    __syncthreads();
    if (lane < 32) {
        int tt = lane >> 3, o2 = lane & 7;
        float to = 0.f;
        #pragma unroll
        for (int ee = 0; ee < 8; ++ee)
            to += gt[wave][tt * 8 + ee] * eo[wave][ee * 8 + o2];
        float pl = to * out_w[tt * 8 + o2];
        #pragma unroll
        for (int off = 4; off; off >>= 1) pl += __shfl_xor(pl, off, 8);
        if (o2 == 0) {
            float logit = pl + out_b[tt];
            out[b * 4 + tt] = 1.f / (1.f + __expf(-logit));
        }
    }
}

// ---------- host ----------
extern "C" void kernel_launch(void* const* d_in, const int* in_sizes, int n_in,
                              void* d_out, int out_size, void* d_ws, size_t ws_size,
                              hipStream_t stream)
{
    const int*   sparse_ids = (const int*)d_in[0];
    const float* dense      = (const float*)d_in[1];
    const int*   feedid     = (const int*)d_in[2];
    const int*   hist_ids   = (const int*)d_in[3];
    const float* emb_tables = (const float*)d_in[4];
    const float* feed_table = (const float*)d_in[5];
    const float* attn_w1    = (const float*)d_in[6];
    const float* attn_b1    = (const float*)d_in[7];
    const float* attn_w2    = (const float*)d_in[8];
    const float* attn_b2    = (const float*)d_in[9];
    const float* dnn_w1     = (const float*)d_in[10];
    const float* dnn_b1     = (const float*)d_in[11];
    const float* dnn_w2     = (const float*)d_in[12];
    const float* dnn_b2     = (const float*)d_in[13];
    const float* expert_w   = (const float*)d_in[14];
    const float* gate_w     = (const float*)d_in[15];
    const float* out_w      = (const float*)d_in[16];
    const float* out_b      = (const float*)d_in[17];
    float* out = (float*)d_out;

    char* ws = (char*)d_ws;
    size_t off = 0;
    auto alloc = [&](size_t bytes) {
        char* p = ws + off;
        off += (bytes + 255) & ~(size_t)255;
        return p;
    };
    u16* WHP_S = (u16*)alloc(131072 * 2);
    u16* WQ_T  = (u16*)alloc(65536 * 2);
    u16* W1D_T = (u16*)alloc((size_t)HID1 * KDNN * 2);
    u16* W2D_T = (u16*)alloc((size_t)HID2 * HID1 * 2);
    u16* AQ    = (u16*)alloc((size_t)BB * FDIM * 2);
    float* QW  = (float*)alloc((size_t)BB * 128 * 4);
    u16* DNNIN = (u16*)alloc((size_t)BB * KDNN * 2);
    u16* Z     = (u16*)alloc((size_t)BB * HID1 * 2);
    float* DOUT= (float*)alloc((size_t)BB * HID2 * 4);
    float* SCP = (float*)alloc((size_t)2 * ROWS * 4);

    prep_weights<<<2112, 256, 0, stream>>>(attn_w1, dnn_w1, dnn_w2,
                                           WHP_S, WQ_T, W1D_T, W2D_T);
    gather_b<<<BB, 256, 0, stream>>>(sparse_ids, dense, feedid, emb_tables,
                                     feed_table, DNNIN, AQ);
    gemm_bt<64, false, false><<<dim3(BB / 64, 1), 256, 0, stream>>>(
        AQ, 512, WQ_T, 512, nullptr, QW, BB, 128, 512);
    din_gemm<<<400, 512, 0, stream>>>(
        hist_ids, feedid, feed_table, WHP_S, QW, attn_b1, attn_w2, SCP);
    softmax_ui<<<BB, 256, 0, stream>>>(SCP, hist_ids, feed_table, DNNIN);
    gemm_bt<64, true, true><<<dim3(BB / 64, HID1 / 128), 256, 0, stream>>>(
        DNNIN, KDNN, W1D_T, KDNN, dnn_b1, Z, BB, HID1, KDNN);
    gemm_bt<64, true, false><<<dim3(BB / 64, 1), 256, 0, stream>>>(
        Z, HID1, W2D_T, HID1, dnn_b2, DOUT, BB, HID2, HID1);
    mmoe_head<<<BB / 4, 256, 0, stream>>>(DOUT, expert_w, gate_w, out_w,
                                          out_b, out);
}

// Round 9
// 174.800 us; speedup vs baseline: 1.1566x; 1.1566x over previous
//
#include <hip/hip_runtime.h>
#include <hip/hip_bf16.h>

typedef unsigned short u16;
typedef unsigned int u32;
typedef __attribute__((ext_vector_type(8))) short short8;   // 8 bf16 for MFMA frags
typedef __attribute__((ext_vector_type(8))) u16 ushort8;
typedef __attribute__((ext_vector_type(4))) float f32x4;

// ---------- constants ----------
#define BB 2048
#define SS 8
#define DNUM 8
#define LL 50
#define EDIM 16
#define FDIM 512
#define HID1 256
#define HID2 128
#define KDNN 1216          // 1160 padded to 64-multiple
#define ROWS (BB*LL)       // 102400

// ---------- helpers ----------
__device__ inline u16 f2bf(float x) {            // HW RNE cvt (compiler packs)
    return __builtin_bit_cast(u16, __float2bfloat16(x));
}
__device__ inline float bf2f(u16 b) {
    u32 u = ((u32)b) << 16;
    return __builtin_bit_cast(float, u);
}
__device__ inline void load16_lds(const void* g, void* l) {
    __builtin_amdgcn_global_load_lds(
        (const __attribute__((address_space(1))) u32*)g,
        (__attribute__((address_space(3))) u32*)l, 16, 0, 0);
}
__device__ inline float wave_sum(float v) {
    #pragma unroll
    for (int off = 32; off > 0; off >>= 1) v += __shfl_xor(v, off, 64);
    return v;
}
__device__ inline float wave_max(float v) {
    #pragma unroll
    for (int off = 32; off > 0; off >>= 1) v = fmaxf(v, __shfl_xor(v, off, 64));
    return v;
}
__device__ inline void cvt8(const float4& a, const float4& b, ushort8& o) {
    o[0]=f2bf(a.x); o[1]=f2bf(a.y); o[2]=f2bf(a.z); o[3]=f2bf(a.w);
    o[4]=f2bf(b.x); o[5]=f2bf(b.y); o[6]=f2bf(b.z); o[7]=f2bf(b.w);
}

// ---------- K0: weight prep (combine + transpose + bf16) ----------
// WHP_S [128n][1024k] PRE-SWIZZLED within each 32-k tile:
//   ks = (k&~31) | ((k&31) ^ ((n&3)<<3))
// so a swizzled ds_read after linear global_load_lds staging of 32-k slices
// spreads the 128B-row-stride bank collisions (residual 4-way, ~free).
//   k<512 -> Wh = W1b-W1c ; k>=512 -> Wp = W1d
__global__ __launch_bounds__(256) void prep_weights(
    const float* __restrict__ w1, const float* __restrict__ dw1,
    const float* __restrict__ dw2,
    u16* __restrict__ WHP_S, u16* __restrict__ WQ_T,
    u16* __restrict__ W1D_T, u16* __restrict__ W2D_T)
{
    int idx = blockIdx.x * 256 + threadIdx.x;
    if (idx < 131072) {
        int n = idx >> 10, k = idx & 1023;
        float v;
        if (k < 512) v = w1[(512 + k) * 128 + n] - w1[(1024 + k) * 128 + n];
        else         v = w1[(1024 + k) * 128 + n];   // 1536 + (k-512)
        int ks = (k & ~31) | ((k & 31) ^ ((n & 3) << 3));
        WHP_S[n * 1024 + ks] = f2bf(v);
    } else if (idx < 196608) {
        int i = idx - 131072;
        int n = i >> 9, k = i & 511;
        WQ_T[n * 512 + k] = f2bf(w1[k * 128 + n] + w1[(1024 + k) * 128 + n]);
    } else if (idx < 507904) {
        int i = idx - 196608;
        int n = i / KDNN, k = i - n * KDNN;
        W1D_T[i] = (k < 1160) ? f2bf(dw1[k * HID1 + n]) : (u16)0;
    } else if (idx < 540672) {
        int i = idx - 507904;
        int n = i >> 8, k = i & 255;
        W2D_T[i] = f2bf(dw2[k * HID2 + n]);
    }
}

// ---------- K1: per-b gather: sparse emb + dense + feed -> dnn_in (bf16), A_q ----------
__global__ __launch_bounds__(256) void gather_b(
    const int* __restrict__ sparse_ids, const float* __restrict__ dense,
    const int* __restrict__ feedid, const float* __restrict__ emb_tables,
    const float* __restrict__ feed_table,
    u16* __restrict__ dnn_in, u16* __restrict__ A_q)
{
    int b = blockIdx.x, t = threadIdx.x;
    u16* drow = dnn_in + (size_t)b * KDNN;
    if (t < 128) {
        int s = t >> 4, e = t & 15;
        int id = sparse_ids[b * SS + s];
        float v = emb_tables[(size_t)s * 1600000 + (size_t)id * EDIM + e];
        drow[t] = f2bf(v);
    } else if (t < 136) {
        drow[t] = f2bf(dense[b * DNUM + (t - 128)]);
    } else if (t < 192) {
        drow[1160 + (t - 136)] = 0;   // K padding
    }
    int fid = feedid[b];
    float2 f = *(const float2*)&feed_table[(size_t)fid * FDIM + t * 2];
    u16 u0 = f2bf(f.x), u1 = f2bf(f.y);
    drow[136 + t * 2] = u0;
    drow[136 + t * 2 + 1] = u1;
    A_q[(size_t)b * FDIM + t * 2] = u0;
    A_q[(size_t)b * FDIM + t * 2 + 1] = u1;
}

// ---------- K2: generic bf16 MFMA GEMM, templated M-tile ----------
template<int BM, bool RELU, bool OUT_BF16>
__global__ __launch_bounds__(256, 4) void gemm_bt(
    const u16* __restrict__ A, int lda,
    const u16* __restrict__ BT, int ldb,
    const float* __restrict__ bias,
    void* __restrict__ Cv, int M, int N, int K)
{
    constexpr int MI = BM / 32;           // frags per wave in M
    __shared__ u16 As[BM * 64];
    __shared__ u16 Bs[128 * 64];
    int m0 = blockIdx.x * BM, n0 = blockIdx.y * 128;
    int tid = threadIdx.x, wave = tid >> 6, lane = tid & 63;
    int lrow = lane >> 3, lk = (lane & 7) * 8;
    f32x4 acc[MI][4];
    f32x4 zz = {0.f, 0.f, 0.f, 0.f};
    #pragma unroll
    for (int i = 0; i < MI; i++)
        #pragma unroll
        for (int j = 0; j < 4; j++) acc[i][j] = zz;
    int wm = (wave >> 1) * (BM / 2), wn = (wave & 1) * 64;

    for (int kt = 0; kt < K; kt += 64) {
        #pragma unroll
        for (int j = 0; j < MI; ++j) {
            int c = wave * MI + j;
            int row = c * 8 + lrow;
            load16_lds(A + (size_t)(m0 + row) * lda + kt + lk, &As[c * 512]);
        }
        #pragma unroll
        for (int j = 0; j < 4; ++j) {
            int c = wave * 4 + j;
            int row = c * 8 + lrow;
            load16_lds(BT + (size_t)(n0 + row) * ldb + kt + lk, &Bs[c * 512]);
        }
        __syncthreads();
        #pragma unroll
        for (int ks = 0; ks < 2; ++ks) {
            int kk = ks * 32 + (lane >> 4) * 8;
            short8 af[MI], bf[4];
            #pragma unroll
            for (int i = 0; i < MI; i++)
                af[i] = *(const short8*)&As[(wm + i * 16 + (lane & 15)) * 64 + kk];
            #pragma unroll
            for (int j = 0; j < 4; j++)
                bf[j] = *(const short8*)&Bs[(wn + j * 16 + (lane & 15)) * 64 + kk];
            #pragma unroll
            for (int i = 0; i < MI; i++)
                #pragma unroll
                for (int j = 0; j < 4; j++)
                    acc[i][j] = __builtin_amdgcn_mfma_f32_16x16x32_bf16(
                        af[i], bf[j], acc[i][j], 0, 0, 0);
        }
        __syncthreads();
    }
    #pragma unroll
    for (int i = 0; i < MI; i++) {
        #pragma unroll
        for (int j = 0; j < 4; j++) {
            #pragma unroll
            for (int r = 0; r < 4; r++) {
                int row = m0 + wm + i * 16 + (lane >> 4) * 4 + r;
                int col = n0 + wn + j * 16 + (lane & 15);
                float v = acc[i][j][r];
                if (bias) v += bias[col];
                if (RELU) v = fmaxf(v, 0.f);
                size_t off = (size_t)row * N + col;
                if (OUT_BF16) ((u16*)Cv)[off] = f2bf(v);
                else ((float*)Cv)[off] = v;
            }
        }
    }
}

// ---------- K3: DIN GEMM v9 — small tiles, high occupancy (4 blocks/CU) ----------
// Block = 64 rows x 128 cols, 256 thr (4 waves, 2m x 2n; wave tile 32x64).
// Per KT=32 step: stage B (16 KB, global_load_lds from pre-swizzled WHP_S),
// gather h straight to regs in the same window (one vmcnt(0) drain covers
// both), q read from a per-block LDS copy (broadcast). LDS ~25 KB, VGPR
// target <=128 -> 4 blocks/CU; cross-block TLP hides the drain stall.
// Epilogue: complete score per row via 16-lane shfl + cross-wave LDS reduce.
__global__ __launch_bounds__(256, 4) void din_gemm(
    const int* __restrict__ hist_ids, const int* __restrict__ feedid,
    const float* __restrict__ feed_table,
    const u16* __restrict__ WHP_S,
    const float* __restrict__ qw, const float* __restrict__ b1,
    const float* __restrict__ w2v, float* __restrict__ scores)
{
    __shared__ u16 BsH[128 * 32];     // 8 KB [n][32k] (swizzled content)
    __shared__ u16 BsP[128 * 32];     // 8 KB
    __shared__ float qls[3 * 512];    // 6 KB: q rows (f32) for b0..b0+2
    __shared__ float qbs[3 * 128];    // qw + b1
    __shared__ float w2s[128];
    __shared__ float sred[64 * 2];

    int t = threadIdx.x, w = t >> 6, lane = t & 63;
    int m0 = blockIdx.x * 64;
    int b0 = m0 / LL;
    int fr = lane & 15, kg = (lane >> 4) * 8;
    int wm = (w >> 1) * 32, wn = (w & 1) * 64;

    // ---- prologue: q rows, qw+b1, w2 into LDS ----
    for (int idx = t; idx < 768; idx += 256) {        // 768 float2 = 3 q rows
        int bi = idx >> 8, d2 = (idx & 255) * 2;
        int bb = b0 + bi; if (bb > BB - 1) bb = BB - 1;
        *(float2*)&qls[bi * 512 + d2] =
            *(const float2*)&feed_table[(size_t)feedid[bb] * FDIM + d2];
    }
    for (int idx = t; idx < 384; idx += 256) {
        int bi = idx >> 7, col = idx & 127;
        int bb = b0 + bi; if (bb > BB - 1) bb = BB - 1;
        qbs[idx] = qw[bb * 128 + col] + b1[col];
    }
    if (t < 128) w2s[t] = w2v[t];

    // ---- per-frag h pointers + q row index (registers, no LDS chain) ----
    const float* hp[2];
    int qb_[2];
    #pragma unroll
    for (int i = 0; i < 2; ++i) {
        int gr = m0 + wm + i * 16 + fr;
        hp[i] = feed_table + (size_t)hist_ids[gr] * FDIM + kg;
        qb_[i] = gr / LL - b0;
    }

    f32x4 acc[2][4];
    f32x4 zz = {0.f, 0.f, 0.f, 0.f};
    #pragma unroll
    for (int i = 0; i < 2; i++)
        #pragma unroll
        for (int j = 0; j < 4; j++) acc[i][j] = zz;

    for (int kt = 0; kt < 512; kt += 32) {
        __syncthreads();             // prev step's B reads done (covers prologue at kt=0)
        // stage B step tile: linear dest, pre-swizzled source
        #pragma unroll
        for (int c = 0; c < 2; ++c) {
            int row = w * 32 + c * 16 + (lane >> 2);
            int ke = (lane & 3) * 8;
            load16_lds(WHP_S + (size_t)row * 1024 + kt + ke,
                       &BsH[(w * 32 + c * 16) * 32]);
            load16_lds(WHP_S + (size_t)row * 1024 + 512 + kt + ke,
                       &BsP[(w * 32 + c * 16) * 32]);
        }
        // gather h for this step (lands during the same drain window)
        float4 h4[2][2];
        #pragma unroll
        for (int i = 0; i < 2; ++i) {
            h4[i][0] = *(const float4*)(hp[i] + kt);
            h4[i][1] = *(const float4*)(hp[i] + kt + 4);
        }
        __syncthreads();             // vmcnt(0): B in LDS, h in regs

        // build A fragments (h, p = h*q) — q broadcast from LDS
        short8 ah[2], ap[2];
        #pragma unroll
        for (int i = 0; i < 2; ++i) {
            float4 q0 = *(const float4*)&qls[qb_[i] * 512 + kt + kg];
            float4 q1 = *(const float4*)&qls[qb_[i] * 512 + kt + kg + 4];
            ushort8 hv, pv;
            cvt8(h4[i][0], h4[i][1], hv);
            float4 p0 = make_float4(h4[i][0].x * q0.x, h4[i][0].y * q0.y,
                                    h4[i][0].z * q0.z, h4[i][0].w * q0.w);
            float4 p1 = make_float4(h4[i][1].x * q1.x, h4[i][1].y * q1.y,
                                    h4[i][1].z * q1.z, h4[i][1].w * q1.w);
            cvt8(p0, p1, pv);
            ah[i] = __builtin_bit_cast(short8, hv);
            ap[i] = __builtin_bit_cast(short8, pv);
        }
        // B fragments (swizzled read; residual 4-way conflict, ~free)
        short8 bh[4], bp[4];
        #pragma unroll
        for (int j = 0; j < 4; ++j) {
            int n = wn + j * 16 + fr;
            int kk = kg ^ ((n & 3) << 3);
            bh[j] = *(const short8*)&BsH[n * 32 + kk];
            bp[j] = *(const short8*)&BsP[n * 32 + kk];
        }
        #pragma unroll
        for (int i = 0; i < 2; ++i)
            #pragma unroll
            for (int j = 0; j < 4; ++j) {
                acc[i][j] = __builtin_amdgcn_mfma_f32_16x16x32_bf16(
                    ah[i], bh[j], acc[i][j], 0, 0, 0);
                acc[i][j] = __builtin_amdgcn_mfma_f32_16x16x32_bf16(
                    ap[i], bp[j], acc[i][j], 0, 0, 0);
            }
    }

    // ---- epilogue: score[row] = sum_col relu(acc + qw + b1) * w2 ----
    #pragma unroll
    for (int i = 0; i < 2; ++i) {
        #pragma unroll
        for (int r = 0; r < 4; ++r) {
            int rl = wm + i * 16 + (lane >> 4) * 4 + r;
            int bi = (m0 + rl) / LL - b0;
            float s = 0.f;
            #pragma unroll
            for (int j = 0; j < 4; ++j) {
                int col = wn + j * 16 + fr;
                float v = acc[i][j][r] + qbs[bi * 128 + col];
                s += fmaxf(v, 0.f) * w2s[col];
            }
            s += __shfl_xor(s, 1, 64);
            s += __shfl_xor(s, 2, 64);
            s += __shfl_xor(s, 4, 64);
            s += __shfl_xor(s, 8, 64);
            if (fr == 0) sred[rl * 2 + (w & 1)] = s;
        }
    }
    __syncthreads();
    if (t < 64) scores[m0 + t] = sred[t * 2] + sred[t * 2 + 1];
}

// ---------- K4: softmax over L + user_interest (re-gather h, L3-hot) ----------
__global__ __launch_bounds__(256) void softmax_ui(
    const float* __restrict__ scores, const int* __restrict__ hist_ids,
    const float* __restrict__ feed_table, u16* __restrict__ dnn_in)
{
    int b = blockIdx.x, t = threadIdx.x;
    int wave = t >> 6, lane = t & 63;
    __shared__ float sc[56];
    __shared__ int hid[56];
    if (t >= 64 && t < 64 + LL) hid[t - 64] = hist_ids[b * LL + (t - 64)];
    if (wave == 0) {
        float x = (lane < LL) ? scores[b * LL + lane] : -1e30f;
        float mx = wave_max(x);
        float e = (lane < LL) ? __expf(x - mx) : 0.f;
        float s = wave_sum(e);
        if (lane < LL) sc[lane] = e / s;
    }
    __syncthreads();
    int d = t * 2;
    float a0 = 0.f, a1 = 0.f;
    #pragma unroll 5
    for (int l = 0; l < LL; ++l) {
        float2 hv = *(const float2*)&feed_table[(size_t)hid[l] * FDIM + d];
        float al = sc[l];
        a0 += al * hv.x;
        a1 += al * hv.y;
    }
    dnn_in[(size_t)b * KDNN + 648 + d] = f2bf(a0);
    dnn_in[(size_t)b * KDNN + 648 + d + 1] = f2bf(a1);
}

// ---------- K5: MMOE + task heads ----------
__global__ __launch_bounds__(256) void mmoe_head(
    const float* __restrict__ dnn_out, const float* __restrict__ expert_w,
    const float* __restrict__ gate_w, const float* __restrict__ out_w,
    const float* __restrict__ out_b, float* __restrict__ out)
{
    int wave = threadIdx.x >> 6, lane = threadIdx.x & 63;
    int b = blockIdx.x * 4 + wave;
    __shared__ float ds[4][128];
    __shared__ float eo[4][64];
    __shared__ float gt[4][32];
    ds[wave][lane] = dnn_out[b * 128 + lane];
    ds[wave][lane + 64] = dnn_out[b * 128 + 64 + lane];
    __syncthreads();
    int e = lane >> 3, o = lane & 7;
    float acc = 0.f;
    for (int k = 0; k < 128; ++k)
        acc += ds[wave][k] * expert_w[(e * 128 + k) * 8 + o];
    eo[wave][lane] = acc;
    if (lane < 32) {
        int tt = lane >> 3, ee = lane & 7;
        float g = 0.f;
        for (int k = 0; k < 128; ++k)
            g += ds[wave][k] * gate_w[(tt * 128 + k) * 8 + ee];
        float m = g;
        #pragma unroll
        for (int off = 4; off; off >>= 1) m = fmaxf(m, __shfl_xor(m, off, 8));
        float ex = __expf(g - m);
        float s = ex;
        #pragma unroll
        for (int off = 4; off; off >>= 1) s += __shfl_xor(s, off, 8);
        gt[wave][lane] = ex / s;
    }
    __syncthreads();
    if (lane < 32) {
        int tt = lane >> 3, o2 = lane & 7;
        float to = 0.f;
        #pragma unroll
        for (int ee = 0; ee < 8; ++ee)
            to += gt[wave][tt * 8 + ee] * eo[wave][ee * 8 + o2];
        float pl = to * out_w[tt * 8 + o2];
        #pragma unroll
        for (int off = 4; off; off >>= 1) pl += __shfl_xor(pl, off, 8);
        if (o2 == 0) {
            float logit = pl + out_b[tt];
            out[b * 4 + tt] = 1.f / (1.f + __expf(-logit));
        }
    }
}

// ---------- host ----------
extern "C" void kernel_launch(void* const* d_in, const int* in_sizes, int n_in,
                              void* d_out, int out_size, void* d_ws, size_t ws_size,
                              hipStream_t stream)
{
    const int*   sparse_ids = (const int*)d_in[0];
    const float* dense      = (const float*)d_in[1];
    const int*   feedid     = (const int*)d_in[2];
    const int*   hist_ids   = (const int*)d_in[3];
    const float* emb_tables = (const float*)d_in[4];
    const float* feed_table = (const float*)d_in[5];
    const float* attn_w1    = (const float*)d_in[6];
    const float* attn_b1    = (const float*)d_in[7];
    const float* attn_w2    = (const float*)d_in[8];
    const float* attn_b2    = (const float*)d_in[9];
    const float* dnn_w1     = (const float*)d_in[10];
    const float* dnn_b1     = (const float*)d_in[11];
    const float* dnn_w2     = (const float*)d_in[12];
    const float* dnn_b2     = (const float*)d_in[13];
    const float* expert_w   = (const float*)d_in[14];
    const float* gate_w     = (const float*)d_in[15];
    const float* out_w      = (const float*)d_in[16];
    const float* out_b      = (const float*)d_in[17];
    float* out = (float*)d_out;

    char* ws = (char*)d_ws;
    size_t off = 0;
    auto alloc = [&](size_t bytes) {
        char* p = ws + off;
        off += (bytes + 255) & ~(size_t)255;
        return p;
    };
    u16* WHP_S = (u16*)alloc(131072 * 2);
    u16* WQ_T  = (u16*)alloc(65536 * 2);
    u16* W1D_T = (u16*)alloc((size_t)HID1 * KDNN * 2);
    u16* W2D_T = (u16*)alloc((size_t)HID2 * HID1 * 2);
    u16* AQ    = (u16*)alloc((size_t)BB * FDIM * 2);
    float* QW  = (float*)alloc((size_t)BB * 128 * 4);
    u16* DNNIN = (u16*)alloc((size_t)BB * KDNN * 2);
    u16* Z     = (u16*)alloc((size_t)BB * HID1 * 2);
    float* DOUT= (float*)alloc((size_t)BB * HID2 * 4);
    float* SCORES = (float*)alloc((size_t)ROWS * 4);

    prep_weights<<<2112, 256, 0, stream>>>(attn_w1, dnn_w1, dnn_w2,
                                           WHP_S, WQ_T, W1D_T, W2D_T);
    gather_b<<<BB, 256, 0, stream>>>(sparse_ids, dense, feedid, emb_tables,
                                     feed_table, DNNIN, AQ);
    gemm_bt<32, false, false><<<dim3(BB / 32, 1), 256, 0, stream>>>(
        AQ, 512, WQ_T, 512, nullptr, QW, BB, 128, 512);
    din_gemm<<<ROWS / 64, 256, 0, stream>>>(
        hist_ids, feedid, feed_table, WHP_S, QW, attn_b1, attn_w2, SCORES);
    softmax_ui<<<BB, 256, 0, stream>>>(SCORES, hist_ids, feed_table, DNNIN);
    gemm_bt<32, true, true><<<dim3(BB / 32, HID1 / 128), 256, 0, stream>>>(
        DNNIN, KDNN, W1D_T, KDNN, dnn_b1, Z, BB, HID1, KDNN);
    gemm_bt<32, true, false><<<dim3(BB / 32, 1), 256, 0, stream>>>(
        Z, HID1, W2D_T, HID1, dnn_b2, DOUT, BB, HID2, HID1);
    mmoe_head<<<BB / 4, 256, 0, stream>>>(DOUT, expert_w, gate_w, out_w,
                                          out_b, out);
}